// Round 1
// 243.563 us; speedup vs baseline: 1.0111x; 1.0111x over previous
//
#include <hip/hip_runtime.h>

typedef __bf16 bf16;
typedef __attribute__((ext_vector_type(4))) __bf16 bf16x4;
typedef __attribute__((ext_vector_type(8))) __bf16 bf16x8;
typedef __attribute__((ext_vector_type(4))) float f32x4;
typedef __attribute__((ext_vector_type(16))) float f32x16;

#define MFMA16(a, b, c) __builtin_amdgcn_mfma_f32_16x16x32_bf16((a), (b), (c), 0, 0, 0)
#define MFMA32(a, b, c) __builtin_amdgcn_mfma_f32_32x32x16_bf16((a), (b), (c), 0, 0, 0)

// RNE fp32->bf16 (epilogue)
__device__ __forceinline__ bf16 tobf(float f) {
    unsigned u = __float_as_uint(f);
    u += 0x7fffu + ((u >> 16) & 1u);
    unsigned short h = (unsigned short)(u >> 16);
    bf16 r;
    __builtin_memcpy(&r, &h, 2);
    return r;
}

// ---------------------------------------------------------------------------
// W [1024][64] fp32 -> Wt [3][64][1024] bf16 (transposed)
// ---------------------------------------------------------------------------
__global__ void wconv_kernel(const float* __restrict__ Wq, const float* __restrict__ Wk,
                             const float* __restrict__ Wv, bf16* __restrict__ Wt) {
    int j = blockIdx.y;
    const float* W = (j == 0) ? Wq : ((j == 1) ? Wk : Wv);
    int idx = blockIdx.x * 256 + threadIdx.x;
    int m = idx >> 6, n = idx & 63;
    Wt[(size_t)j * 65536 + (size_t)n * 1024 + m] = tobf(W[idx]);
}

// ---------------------------------------------------------------------------
// Projections v6: A is NEVER staged in LDS. Each wave owns 16 rows and streams
// A-fragments global->reg directly in MFMA fragment layout (lane(l16,quad)
// reads 32B at row=l16, k=c*32+quad*8; 4 quads cover a contiguous 128B row
// segment -> full cache-line use). One-tile register prefetch for A; bf16
// conversion in-register. Only B (W tile, L2-resident) goes through LDS,
// double-buffered -> ONE barrier per K-tile, draining lgkmcnt only. All
// global loads stay in flight across barriers; the HBM pipe never drains.
// LDS 34.8KB (B dbuf, V-transpose tile aliases it) -> 4 blocks/CU.
// ---------------------------------------------------------------------------
__launch_bounds__(256, 4)
__global__ void proj_kernel(const float* __restrict__ Q, const float* __restrict__ K,
                            const float* __restrict__ V, const bf16* __restrict__ Wt,
                            const float* __restrict__ bq, const float* __restrict__ bk,
                            const float* __restrict__ bv,
                            bf16* __restrict__ q_ws, bf16* __restrict__ k_ws,
                            bf16* __restrict__ vT_ws) {
    const int j = blockIdx.y;
    const float* In   = (j == 0) ? Q : ((j == 1) ? K : V);
    const float* bias = (j == 0) ? bq : ((j == 1) ? bk : bv);
    const bf16* W = Wt + (size_t)j * 65536;

    __shared__ bf16 Bs[2][64][136];   // B tile bf16 [buf][n][k], padded (<=8-way on b128)

    const int tid = threadIdx.x;
    const int wave = tid >> 6, lane = tid & 63;
    const int quad = lane >> 4, l16 = lane & 15;
    const int rbase = blockIdx.x * 64;
    const int myrow = rbase + wave * 16 + l16;

    // Per-lane A stream base; all K-tile/c offsets are compile-time immediates
    // (max 7*512 + 3*128 + 16 < 4096B, fits the 13-bit signed global offset).
    const float* abase = In + (size_t)myrow * 1024 + quad * 8;

    // B staging map (cooperative, coalesced): u = i*256+tid -> row=u>>4,
    // granule g=u&15 (16B bf16).
    int brow[4], bg[4];
    const bf16* bpt[4];
#pragma unroll
    for (int i = 0; i < 4; i++) {
        int u = i * 256 + tid;
        brow[i] = u >> 4; bg[i] = u & 15;
        bpt[i] = W + (size_t)brow[i] * 1024 + bg[i] * 8;
    }

    // prologue: issue A(0) and B(0) loads
    f32x4 an[8];
#pragma unroll
    for (int c = 0; c < 4; c++) {
        an[2 * c]     = *(const f32x4*)(abase + c * 32);
        an[2 * c + 1] = *(const f32x4*)(abase + c * 32 + 4);
    }
    bf16x8 bbuf[4];
#pragma unroll
    for (int i = 0; i < 4; i++) bbuf[i] = *(const bf16x8*)(bpt[i]);

    f32x4 acc[4];
#pragma unroll
    for (int nt = 0; nt < 4; nt++) acc[nt] = {0.f, 0.f, 0.f, 0.f};

    bf16x8 acur[4];

#pragma unroll
    for (int it = 0; it < 8; it++) {
        // convert this tile's A to bf16 (vmcnt wait covers only these 8 loads,
        // issued a full iteration ago)
#pragma unroll
        for (int c = 0; c < 4; c++) {
            bf16x8 v;
            v[0] = (bf16)an[2 * c][0];     v[1] = (bf16)an[2 * c][1];
            v[2] = (bf16)an[2 * c][2];     v[3] = (bf16)an[2 * c][3];
            v[4] = (bf16)an[2 * c + 1][0]; v[5] = (bf16)an[2 * c + 1][1];
            v[6] = (bf16)an[2 * c + 1][2]; v[7] = (bf16)an[2 * c + 1][3];
            acur[c] = v;
        }
        // issue next tile's A loads immediately -> in flight across the whole
        // stage + barrier + MFMA phase
        if (it < 7) {
            const float* ap = abase + (it + 1) * 128;
#pragma unroll
            for (int c = 0; c < 4; c++) {
                an[2 * c]     = *(const f32x4*)(ap + c * 32);
                an[2 * c + 1] = *(const f32x4*)(ap + c * 32 + 4);
            }
        }
        // commit B prefetch regs to LDS buf (fine-grained vmcnt wait on the
        // 4 B loads only; the 8 newer A loads stay outstanding)
#pragma unroll
        for (int i = 0; i < 4; i++) *(bf16x8*)&Bs[it & 1][brow[i]][bg[i] * 8] = bbuf[i];
        if (it < 7) {
#pragma unroll
            for (int i = 0; i < 4; i++) bbuf[i] = *(const bf16x8*)(bpt[i] + (it + 1) * 128);
        }
        __syncthreads();   // lgkmcnt drain only; single barrier per K-tile (dbuf)

#pragma unroll
        for (int c = 0; c < 4; c++) {
#pragma unroll
            for (int nt = 0; nt < 4; nt++) {
                bf16x8 bv = *(const bf16x8*)&Bs[it & 1][nt * 16 + l16][c * 32 + quad * 8];
                acc[nt] = MFMA16(acur[c], bv, acc[nt]);
            }
        }
        // no trailing barrier: next iteration writes the OTHER buffer; the
        // write of buf (it&1) at it+2 is ordered by the barrier at it+1.
    }

    const float scale = (j == 0) ? 0.125f * 1.44269504088896f : 1.0f;

    if (j != 2) {
        bf16* dst = (j == 0) ? q_ws : k_ws;
#pragma unroll
        for (int nt = 0; nt < 4; nt++) {
            int n = nt * 16 + l16;
            float bb = bias[n];
#pragma unroll
            for (int r4 = 0; r4 < 4; r4++) {
                int row = rbase + wave * 16 + quad * 4 + r4;
                dst[(size_t)row * 64 + n] = tobf((acc[nt][r4] + bb) * scale);
            }
        }
    } else {
        // v: transpose via LDS. vtile (9216B) aliases Bs[0] (17408B); the last
        // compute reads Bs[1] only -> disjoint, no barrier needed before write.
        bf16 (*vtile)[72] = (bf16(*)[72])Bs;
#pragma unroll
        for (int nt = 0; nt < 4; nt++) {
            int n = nt * 16 + l16;
            float bb = bias[n];
#pragma unroll
            for (int r4 = 0; r4 < 4; r4++) {
                vtile[n][wave * 16 + quad * 4 + r4] = tobf(acc[nt][r4] + bb);
            }
        }
        __syncthreads();
        int bi = rbase >> 12, t0 = rbase & 4095;
        int d = tid >> 2, part = (tid & 3) * 16;
        bf16x8 x0 = *(const bf16x8*)&vtile[d][part];
        bf16x8 x1 = *(const bf16x8*)&vtile[d][part + 8];
        bf16* dst = vT_ws + (size_t)(bi * 64 + d) * 4096 + t0 + part;
        *(bf16x8*)dst = x0;
        *(bf16x8*)(dst + 8) = x1;
    }
}

// ---------------------------------------------------------------------------
// Flash attention v3 (unchanged): no-max softmax, S^T trick, K-split.
// ---------------------------------------------------------------------------
__launch_bounds__(256, 4)
__global__ void attn_kernel(const bf16* __restrict__ q_ws, const bf16* __restrict__ k_ws,
                            const bf16* __restrict__ vT_ws,
                            float* __restrict__ po, float* __restrict__ pl,
                            float* __restrict__ out, int keys_per_split, int direct) {
    const int b = blockIdx.z, split = blockIdx.y;
    const int tid = threadIdx.x, wave = tid >> 6, lane = tid & 63;
    const int l32 = lane & 31, h = lane >> 5;
    const int sw = l32 & 7;

    __shared__ bf16 kt[64][64];
    __shared__ bf16 vt[64][64];
    __shared__ bf16 pt[4][32][64];

    const int qrow0 = b * 4096 + blockIdx.x * 128 + wave * 32;

    bf16x8 qf[4];
    const bf16* qp = q_ws + (size_t)(qrow0 + l32) * 64 + h * 8;
#pragma unroll
    for (int c = 0; c < 4; c++) qf[c] = *(const bf16x8*)(qp + c * 16);

    f32x16 o0, o1;
    float l_lane = 0.f;
#pragma unroll
    for (int i = 0; i < 16; i++) { o0[i] = 0.f; o1[i] = 0.f; }

    const int key0 = split * keys_per_split;
    const int srow = tid >> 3;
    const int sg = tid & 7;
    const int sgk = sg ^ (srow & 7);
    const bf16* kg = k_ws + (size_t)(b * 4096 + key0 + srow) * 64 + sg * 8;
    const bf16* vg = vT_ws + (size_t)(b * 64 + srow) * 4096 + key0 + sg * 8;

    uint4 kv0 = *(const uint4*)kg;
    uint4 kv1 = *(const uint4*)(kg + 2048);
    uint4 vv0 = *(const uint4*)vg;
    uint4 vv1 = *(const uint4*)(vg + 131072);

    for (int t0 = 0; t0 < keys_per_split; t0 += 64) {
        __syncthreads();
        *(uint4*)&kt[srow][sgk * 8]      = kv0;
        *(uint4*)&kt[srow + 32][sgk * 8] = kv1;
        *(uint4*)&vt[srow][sgk * 8]      = vv0;
        *(uint4*)&vt[srow + 32][sgk * 8] = vv1;
        if (t0 + 64 < keys_per_split) {
            kv0 = *(const uint4*)(kg + (size_t)(t0 + 64) * 64);
            kv1 = *(const uint4*)(kg + (size_t)(t0 + 64) * 64 + 2048);
            vv0 = *(const uint4*)(vg + t0 + 64);
            vv1 = *(const uint4*)(vg + t0 + 64 + 131072);
        }
        __syncthreads();

#pragma unroll
        for (int kt32 = 0; kt32 < 2; kt32++) {
            f32x16 s;
#pragma unroll
            for (int i = 0; i < 16; i++) s[i] = 0.f;
#pragma unroll
            for (int c = 0; c < 4; c++) {
                bf16x8 kf = *(const bf16x8*)(&kt[kt32 * 32 + l32][((2 * c + h) ^ sw) * 8]);
                s = MFMA32(kf, qf[c], s);
            }
#pragma unroll
            for (int g = 0; g < 4; g++) {
                float p0 = __builtin_amdgcn_exp2f(s[4 * g + 0]);
                float p1 = __builtin_amdgcn_exp2f(s[4 * g + 1]);
                float p2 = __builtin_amdgcn_exp2f(s[4 * g + 2]);
                float p3 = __builtin_amdgcn_exp2f(s[4 * g + 3]);
                l_lane += (p0 + p1) + (p2 + p3);
                bf16x4 pk;
                pk[0] = (bf16)p0; pk[1] = (bf16)p1; pk[2] = (bf16)p2; pk[3] = (bf16)p3;
                int gp = (kt32 * 4 + g) ^ sw;
                *(bf16x4*)(&pt[wave][l32][gp * 8 + 4 * h]) = pk;
            }
        }

#pragma unroll
        for (int tc = 0; tc < 4; tc++) {
            int gp = ((2 * tc + h) ^ sw) * 8;
            bf16x8 pf  = *(const bf16x8*)(&pt[wave][l32][gp]);
            bf16x8 vf0 = *(const bf16x8*)(&vt[l32][gp]);
            bf16x8 vf1 = *(const bf16x8*)(&vt[32 + l32][gp]);
            o0 = MFMA32(pf, vf0, o0);
            o1 = MFMA32(pf, vf1, o1);
        }
    }

    l_lane += __shfl_xor(l_lane, 32);

    if (direct) {
        float* orow = out + (size_t)qrow0 * 64;
#pragma unroll
        for (int i = 0; i < 16; i++) {
            int R = (i & 3) + 8 * (i >> 2) + 4 * h;
            float inv = 1.0f / __shfl(l_lane, R);
            orow[(size_t)R * 64 + l32]      = o0[i] * inv;
            orow[(size_t)R * 64 + 32 + l32] = o1[i] * inv;
        }
    } else {
        size_t prow = (size_t)split * 16384 + qrow0;
        float* pob = po + prow * 64;
#pragma unroll
        for (int i = 0; i < 16; i++) {
            int R = (i & 3) + 8 * (i >> 2) + 4 * h;
            pob[(size_t)R * 64 + l32]      = o0[i];
            pob[(size_t)R * 64 + 32 + l32] = o1[i];
        }
        if (h == 0) pl[prow + l32] = l_lane;
    }
}

// ---------------------------------------------------------------------------
// Combine K-split partials: out = sum(po) / sum(pl)
// ---------------------------------------------------------------------------
__launch_bounds__(256)
__global__ void combine_kernel(const float* __restrict__ po, const float* __restrict__ pl,
                               float* __restrict__ out, int nsplit) {
    int idx = blockIdx.x * 256 + threadIdx.x;
    int row = idx >> 6;
    float so = 0.f, sl = 0.f;
    for (int s = 0; s < nsplit; s++) {
        so += po[(size_t)s * 1048576 + idx];
        sl += pl[(size_t)s * 16384 + row];
    }
    out[idx] = so / sl;
}

// ---------------------------------------------------------------------------
extern "C" void kernel_launch(void* const* d_in, const int* in_sizes, int n_in,
                              void* d_out, int out_size, void* d_ws, size_t ws_size,
                              hipStream_t stream) {
    const float* Q  = (const float*)d_in[0];
    const float* K  = (const float*)d_in[1];
    const float* V  = (const float*)d_in[2];
    const float* Wq = (const float*)d_in[3];
    const float* bq = (const float*)d_in[4];
    const float* Wk = (const float*)d_in[5];
    const float* bk = (const float*)d_in[6];
    const float* Wv = (const float*)d_in[7];
    const float* bv = (const float*)d_in[8];
    float* out = (float*)d_out;

    char* ws = (char*)d_ws;
    bf16* Wt    = (bf16*)ws;                              // 384 KB
    bf16* q_ws  = (bf16*)(ws + 393216);                   // 2 MB
    bf16* k_ws  = (bf16*)(ws + 393216 + 2097152);         // 2 MB
    bf16* vT_ws = (bf16*)(ws + 393216 + 2 * 2097152);     // 2 MB
    const size_t base = 393216 + 3 * 2097152;

    const size_t per_split = 16384u * 4u + 1048576u * 4u;
    int nsplit = 1;
    if (ws_size >= base + 8 * per_split) nsplit = 8;
    else if (ws_size >= base + 4 * per_split) nsplit = 4;
    else if (ws_size >= base + 2 * per_split) nsplit = 2;

    float* pl = (float*)(ws + base);
    float* po = (float*)(ws + base + (size_t)nsplit * 65536);

    hipLaunchKernelGGL(wconv_kernel, dim3(256, 3), dim3(256), 0, stream, Wq, Wk, Wv, Wt);
    hipLaunchKernelGGL(proj_kernel, dim3(256, 3), dim3(256), 0, stream,
                       Q, K, V, Wt, bq, bk, bv, q_ws, k_ws, vT_ws);
    hipLaunchKernelGGL(attn_kernel, dim3(32, nsplit, 4), dim3(256), 0, stream,
                       q_ws, k_ws, vT_ws, po, pl, out, 4096 / nsplit, nsplit == 1 ? 1 : 0);
    if (nsplit > 1) {
        hipLaunchKernelGGL(combine_kernel, dim3(4096), dim3(256), 0, stream, po, pl, out, nsplit);
    }
}